// Round 4
// baseline (157.062 us; speedup 1.0000x reference)
//
#include <hip/hip_runtime.h>
#include <stdint.h>

#define NJ 19
#define ROOT_SCALE 200.0f
#define BLOCK 64            // 1 wave per block: no barriers, only counted waitcnts
#define ROWF 76             // floats per batch row (19 joints * 4)
#define ROWV 19             // float4s per batch row
#define SLABF (BLOCK * ROWF)   // 4864 floats per 64-row slab
#define ROOTF (BLOCK * 3)      // 192 floats of root per slab

typedef const __attribute__((address_space(1))) uint32_t* gptr_t;
typedef __attribute__((address_space(3))) uint32_t* lptr_t;

struct Xform { float r[9]; float t[3]; };

__device__ __forceinline__ void quat_rt(float w, float x, float y, float z,
                                        float tx, float ty, float tz, Xform& o) {
    float ts = 2.0f / (w*w + x*x + y*y + z*z);
    o.r[0] = 1.0f - ts*(y*y + z*z); o.r[1] = ts*(x*y - z*w);        o.r[2] = ts*(x*z + y*w);
    o.r[3] = ts*(x*y + z*w);        o.r[4] = 1.0f - ts*(x*x + z*z); o.r[5] = ts*(y*z - x*w);
    o.r[6] = ts*(x*z - y*w);        o.r[7] = ts*(y*z + x*w);        o.r[8] = 1.0f - ts*(x*x + y*y);
    o.t[0] = o.r[0]*tx + o.r[1]*ty + o.r[2]*tz;
    o.t[1] = o.r[3]*tx + o.r[4]*ty + o.r[5]*tz;
    o.t[2] = o.r[6]*tx + o.r[7]*ty + o.r[8]*tz;
}

__device__ __forceinline__ void compose(const Xform& p, const Xform& l, Xform& o) {
#pragma unroll
    for (int i = 0; i < 3; ++i) {
        o.r[i*3+0] = p.r[i*3+0]*l.r[0] + p.r[i*3+1]*l.r[3] + p.r[i*3+2]*l.r[6];
        o.r[i*3+1] = p.r[i*3+0]*l.r[1] + p.r[i*3+1]*l.r[4] + p.r[i*3+2]*l.r[7];
        o.r[i*3+2] = p.r[i*3+0]*l.r[2] + p.r[i*3+1]*l.r[5] + p.r[i*3+2]*l.r[8];
        o.t[i]     = p.r[i*3+0]*l.t[0] + p.r[i*3+1]*l.t[1] + p.r[i*3+2]*l.t[2] + p.t[i];
    }
}

// Issue one slab's load group: exactly 20 VMEM ops (19 joint + 1 root).
// jb/rb are always the *static* arrays after inlining -> AA sees distinct objects.
__device__ __forceinline__ void issue_group(const float* __restrict__ joint,
                                            const float* __restrict__ root,
                                            long long slab, float* jb, float* rb, int tid) {
#pragma unroll
    for (int i = 0; i < ROWV; ++i) {
        __builtin_amdgcn_global_load_lds(
            (gptr_t)(joint + slab * SLABF + (long long)(i * BLOCK + tid) * 4),
            (lptr_t)(jb + i * BLOCK * 4), 16, 0, 0);
    }
    if (tid < 48) {  // 48 lanes x 16 B = 768 B of root for this slab; 1 VMEM op
        __builtin_amdgcn_global_load_lds(
            (gptr_t)(root + slab * ROOTF + tid * 4),
            (lptr_t)rb, 16, 0, 0);
    }
}

// FK chain for one slab resident in (jb, rb); emits exactly 19 global stores.
__device__ __forceinline__ void compute_store(float* jb, const float* rb,
                                              const float* tx, const float* ty, const float* tz,
                                              float* __restrict__ out, long long slab, int tid) {
    float* row = jb + tid * ROWF;
    const float rx = rb[tid*3 + 0] * ROOT_SCALE;
    const float ry = rb[tid*3 + 1] * ROOT_SCALE;
    const float rz = rb[tid*3 + 2] * ROOT_SCALE;

    Xform cur, sv0, sv2, loc;
#pragma unroll
    for (int j = 0; j < NJ; ++j) {
        float4 q = *(const float4*)(&row[j*4]);           // (w,x,y,z)
        quat_rt(q.x, q.y, q.z, q.w, tx[j], ty[j], tz[j], loc);
        if (j == 0) {
            cur = loc;
        } else {
            Xform nxt;
            if (j == 5 || j == 9)        compose(sv2, loc, nxt);   // parent = 2
            else if (j == 13 || j == 16) compose(sv0, loc, nxt);   // parent = 0
            else                         compose(cur, loc, nxt);   // parent = j-1
            cur = nxt;
        }
        if (j == 0) sv0 = cur;
        if (j == 2) sv2 = cur;
        float4 o;
        o.x = cur.t[0] + rx;
        o.y = cur.t[1] + ry;
        o.z = cur.t[2] + rz;
        o.w = 1.0f;                                       // M[3][3] exactly
        *(float4*)(&row[j*4]) = o;
    }

    // coalesced writeback: LDS is a linear mirror of the slab -> 19 stores
    const long long gb = slab * SLABF;
#pragma unroll
    for (int i = 0; i < ROWV; ++i) {
        const int v = i * BLOCK + tid;
        *(float4*)(out + gb + (long long)v * 4) = *(const float4*)(jb + v * 4);
    }
}

__global__ __launch_bounds__(BLOCK) void fk_pipe(
    const float* __restrict__ root, const float* __restrict__ joint,
    const float* __restrict__ offs, float* __restrict__ out, int nslab)
{
    // Two DISTINCT static buffers (not a [2][...] array indexed at runtime):
    // after inlining, every LDS access names a specific object, so alias
    // analysis can prove ds_read(jbA) independent of in-flight gload_lds->jbB
    // and does NOT insert its own s_waitcnt vmcnt(0) drain.
    __shared__ float jbA[SLABF]; __shared__ float jbB[SLABF];   // 2 x 19456 B
    __shared__ float rbA[ROOTF]; __shared__ float rbB[ROOTF];   // 2 x   768 B
    const int tid = threadIdx.x;

    // Hoist thread-uniform joint offsets; drain so in-loop vmcnt counts are exact.
    float tx[NJ], ty[NJ], tz[NJ];
#pragma unroll
    for (int j = 0; j < NJ; ++j) {
        tx[j] = offs[j*16 + 3]; ty[j] = offs[j*16 + 7]; tz[j] = offs[j*16 + 11];
    }
    asm volatile("s_waitcnt vmcnt(0) lgkmcnt(0)" ::: "memory");

    const int stride = gridDim.x;
    long long s = blockIdx.x;                 // grid <= nslab, so s < nslab

    // ---- prologue: slab s into A, slab s+stride into B ----
    issue_group(joint, root, s, jbA, rbA, tid);
    long long n1 = s + stride;
    if (n1 < nslab) {
        issue_group(joint, root, n1, jbB, rbB, tid);
        asm volatile("s_waitcnt vmcnt(20)" ::: "memory");   // drain A-group only
    } else {
        asm volatile("s_waitcnt vmcnt(0)" ::: "memory");
    }
    compute_store(jbA, rbA, tx, ty, tz, out, s, tid);
    s = n1;

    // ---- steady state: strict A/B alternation, all buffer refs static ----
    // Invariant at phase top: outstanding = [group(cur) 20][stores(prev) 19].
    // Issue group(next) (+20) then wait vmcnt(39): in-order retirement drains
    // exactly group(cur); prefetch + stores stay in flight (T4: never drain 0).
    while (s < nslab) {
        {   // phase: B resident, prefetch into A
            long long nxt = s + stride;
            if (nxt < nslab) {
                issue_group(joint, root, nxt, jbA, rbA, tid);
                asm volatile("s_waitcnt vmcnt(39)" ::: "memory");
            } else {
                asm volatile("s_waitcnt vmcnt(19)" ::: "memory");
            }
            compute_store(jbB, rbB, tx, ty, tz, out, s, tid);
            s = nxt;
        }
        if (s >= nslab) break;
        {   // phase: A resident, prefetch into B
            long long nxt = s + stride;
            if (nxt < nslab) {
                issue_group(joint, root, nxt, jbB, rbB, tid);
                asm volatile("s_waitcnt vmcnt(39)" ::: "memory");
            } else {
                asm volatile("s_waitcnt vmcnt(19)" ::: "memory");
            }
            compute_store(jbA, rbA, tx, ty, tz, out, s, tid);
            s = nxt;
        }
    }
    // trailing stores drain at end-of-program
}

// Tail (<64 rows): trivial per-thread path, traffic negligible.
__global__ void fk_tail(const float* __restrict__ root, const float* __restrict__ joint,
                        const float* __restrict__ offs, float* __restrict__ out,
                        int start, int batch)
{
    const int b = start + threadIdx.x;
    if (b >= batch) return;
    const long long base = (long long)b * ROWF;
    const float rx = root[(long long)b*3 + 0] * ROOT_SCALE;
    const float ry = root[(long long)b*3 + 1] * ROOT_SCALE;
    const float rz = root[(long long)b*3 + 2] * ROOT_SCALE;
    Xform cur, sv0, sv2, loc;
#pragma unroll
    for (int j = 0; j < NJ; ++j) {
        float4 q = *(const float4*)(joint + base + j*4);
        quat_rt(q.x, q.y, q.z, q.w, offs[j*16+3], offs[j*16+7], offs[j*16+11], loc);
        if (j == 0) cur = loc;
        else {
            Xform nxt;
            if (j == 5 || j == 9)        compose(sv2, loc, nxt);
            else if (j == 13 || j == 16) compose(sv0, loc, nxt);
            else                         compose(cur, loc, nxt);
            cur = nxt;
        }
        if (j == 0) sv0 = cur;
        if (j == 2) sv2 = cur;
        float4 o; o.x = cur.t[0]+rx; o.y = cur.t[1]+ry; o.z = cur.t[2]+rz; o.w = 1.0f;
        *(float4*)(out + base + j*4) = o;
    }
}

extern "C" void kernel_launch(void* const* d_in, const int* in_sizes, int n_in,
                              void* d_out, int out_size, void* d_ws, size_t ws_size,
                              hipStream_t stream) {
    const float* root  = (const float*)d_in[0];  // (B,3)
    const float* joint = (const float*)d_in[1];  // (B,76)
    const float* offs  = (const float*)d_in[2];  // (19,4,4)
    float* out = (float*)d_out;                  // (B,19,4)
    const int batch = in_sizes[1] / ROWF;
    const int nslab = batch / BLOCK;
    const int tail  = batch - nslab * BLOCK;
    if (nslab > 0) {
        const int grid = nslab < 1024 ? nslab : 1024;   // 4 blocks/CU (LDS-bound)
        fk_pipe<<<grid, BLOCK, 0, stream>>>(root, joint, offs, out, nslab);
    }
    if (tail > 0) {
        fk_tail<<<1, BLOCK, 0, stream>>>(root, joint, offs, out, nslab * BLOCK, batch);
    }
}